// Round 4
// baseline (3835.510 us; speedup 1.0000x reference)
//
#include <hip/hip_runtime.h>
#include <math.h>

#define N_PTS 4096
#define BATCH 4
#define KNN 10

__device__ __forceinline__ bool better(float v1, int i1, float v2, int i2) {
    return (v1 > v2) || (v1 == v2 && i1 < i2);
}

__device__ __forceinline__ unsigned f2key(float x) {
    unsigned u = __float_as_uint(x);
    return (u & 0x80000000u) ? ~u : (u | 0x80000000u);
}
__device__ __forceinline__ float key2f(unsigned k) {
    unsigned u = (k & 0x80000000u) ? (k & 0x7FFFFFFFu) : ~k;
    return __uint_as_float(u);
}

__device__ __forceinline__ float lrelu(float h) { return (h > 0.f) ? h : 0.2f * h; }

// ---------------- squared norms ----------------
__global__ void sq_kernel(const float* __restrict__ x, int xstr, int D,
                          float* __restrict__ sq) {
    int g = blockIdx.x * blockDim.x + threadIdx.x;
    if (g >= BATCH * N_PTS) return;
    const float* row = x + (long)g * xstr;
    float s = 0.f;
    if ((D & 3) == 0) {
        for (int c = 0; c < D; c += 4) {
            float4 v = *(const float4*)&row[c];
            s += v.x * v.x + v.y * v.y + v.z * v.z + v.w * v.w;
        }
    } else {
        for (int c = 0; c < D; ++c) { float v = row[c]; s += v * v; }
    }
    sq[g] = s;
}

// ---------------- neg-distance tile GEMM, 128x128 tile, 8x8/thread --------
// B-fragment columns split tx*4 / 64+tx*4 to kill 4-way LDS bank conflicts.
__global__ __launch_bounds__(256) void dist_kernel(const float* __restrict__ x,
                                                   const float* __restrict__ sq,
                                                   float* __restrict__ dist,
                                                   int xstr, int D, int row0) {
    __shared__ float As[16][132];
    __shared__ float Bs[16][132];
    int b = blockIdx.z;
    const float* xb = x + (long)b * N_PTS * xstr;
    const float* sqb = sq + b * N_PTS;
    float* db = dist + (long)b * 1024 * N_PTS;
    int r0 = row0 + blockIdx.y * 128;
    int c0 = blockIdx.x * 128;
    int tx = threadIdx.x & 15, ty = threadIdx.x >> 4;
    float acc[8][8] = {};
    int nk = (D + 15) >> 4;
    for (int kt = 0; kt < nk; ++kt) {
        int k0 = kt * 16;
        for (int e = threadIdx.x; e < 2048; e += 256) {
            int kk = e & 15, r = e >> 4;
            int c = k0 + kk;
            As[kk][r] = (c < D) ? xb[(long)(r0 + r) * xstr + c] : 0.f;
            Bs[kk][r] = (c < D) ? xb[(long)(c0 + r) * xstr + c] : 0.f;
        }
        __syncthreads();
        #pragma unroll
        for (int kk = 0; kk < 16; ++kk) {
            float a[8], bb[8];
            *(float4*)&a[0] = *(float4*)&As[kk][ty * 8];
            *(float4*)&a[4] = *(float4*)&As[kk][ty * 8 + 4];
            *(float4*)&bb[0] = *(float4*)&Bs[kk][tx * 4];
            *(float4*)&bb[4] = *(float4*)&Bs[kk][64 + tx * 4];
            #pragma unroll
            for (int i = 0; i < 8; ++i)
                #pragma unroll
                for (int j = 0; j < 8; ++j) acc[i][j] += a[i] * bb[j];
        }
        __syncthreads();
    }
    int cb0 = c0 + tx * 4;
    int cb1 = c0 + 64 + tx * 4;
    #pragma unroll
    for (int i = 0; i < 8; ++i) {
        int lr = blockIdx.y * 128 + ty * 8 + i;
        float sr = sqb[r0 + ty * 8 + i];
        float4 v0, v1;
        v0.x = 2.f * acc[i][0] - sr - sqb[cb0 + 0];
        v0.y = 2.f * acc[i][1] - sr - sqb[cb0 + 1];
        v0.z = 2.f * acc[i][2] - sr - sqb[cb0 + 2];
        v0.w = 2.f * acc[i][3] - sr - sqb[cb0 + 3];
        v1.x = 2.f * acc[i][4] - sr - sqb[cb1 + 0];
        v1.y = 2.f * acc[i][5] - sr - sqb[cb1 + 1];
        v1.z = 2.f * acc[i][6] - sr - sqb[cb1 + 2];
        v1.w = 2.f * acc[i][7] - sr - sqb[cb1 + 3];
        *(float4*)&db[(long)lr * N_PTS + cb0] = v0;
        *(float4*)&db[(long)lr * N_PTS + cb1] = v1;
    }
}

// ---------------- wave-per-row top-(k+1): bulk-load row to regs, then scan -
__global__ __launch_bounds__(256) void topk_kernel(const float* __restrict__ dist,
                                                   int* __restrict__ idxout, int row0) {
    int b = blockIdx.y;
    int wave = threadIdx.x >> 6;
    int lane = threadIdx.x & 63;
    int row_local = blockIdx.x * 4 + wave;
    const float4* d4 = (const float4*)(dist + (long)b * 1024 * N_PTS +
                                       (long)row_local * N_PTS);
    // bulk load: 16 coalesced float4 loads, all in flight at once
    float4 buf[16];
    #pragma unroll
    for (int t = 0; t < 16; ++t) buf[t] = d4[t * 64 + lane];
    float lv[11]; int li[11];
    #pragma unroll
    for (int j = 0; j < 11; ++j) { lv[j] = -INFINITY; li[j] = 0x7FFFFFFF; }
    #pragma unroll
    for (int t = 0; t < 16; ++t) {
        float vv[4] = {buf[t].x, buf[t].y, buf[t].z, buf[t].w};
        #pragma unroll
        for (int e = 0; e < 4; ++e) {
            float v = vv[e];
            int c = t * 256 + lane * 4 + e;
            if (better(v, c, lv[10], li[10])) {
                lv[10] = v; li[10] = c;
                #pragma unroll
                for (int j = 10; j > 0; --j) {
                    if (better(lv[j], li[j], lv[j - 1], li[j - 1])) {
                        float tv = lv[j]; lv[j] = lv[j - 1]; lv[j - 1] = tv;
                        int ti = li[j]; li[j] = li[j - 1]; li[j - 1] = ti;
                    }
                }
            }
        }
    }
    int keep = 0;
    #pragma unroll
    for (int r = 0; r < 11; ++r) {
        float bv = lv[0]; int bi = li[0];
        #pragma unroll
        for (int off = 32; off > 0; off >>= 1) {
            float ov = __shfl_xor(bv, off);
            int oi = __shfl_xor(bi, off);
            if (better(ov, oi, bv, bi)) { bv = ov; bi = oi; }
        }
        if (li[0] == bi) {
            #pragma unroll
            for (int j = 0; j < 10; ++j) { lv[j] = lv[j + 1]; li[j] = li[j + 1]; }
            lv[10] = -INFINITY; li[10] = 0x7FFFFFFF;
        }
        if (r > 0 && lane == r - 1) keep = bi;
    }
    if (lane < 10)
        idxout[((long)b * N_PTS + row0 + row_local) * KNN + lane] = keep;
}

// ---------------- edge conv L1 (DIN=3, fused path) ----------------
template <int DIN, int DOUT, int PTS, int TPP>
__global__ __launch_bounds__(256) void edgeconv_kernel(
    const float* __restrict__ x, int xstr, const int* __restrict__ idx,
    const float* __restrict__ w, const float* __restrict__ gamma,
    const float* __restrict__ beta, float* __restrict__ out, int outoff) {
    constexpr int DP = DIN + 1;
    constexpr int C2 = 2 * DIN;
    __shared__ float ctr[PTS][DP];
    __shared__ float nm[PTS][KNN][DP];
    int p0 = blockIdx.x * PTS;
    for (int e = threadIdx.x; e < PTS * DIN; e += 256) {
        int p = e / DIN, c = e - p * DIN;
        ctr[p][c] = x[(long)(p0 + p) * xstr + c];
    }
    __syncthreads();
    for (int e = threadIdx.x; e < PTS * KNN * DIN; e += 256) {
        int p = e / (KNN * DIN);
        int rem = e - p * (KNN * DIN);
        int kk = rem / DIN, c = rem - kk * DIN;
        int g = p0 + p;
        int nb = (g & ~(N_PTS - 1)) + idx[(long)g * KNN + kk];
        nm[p][kk][c] = x[(long)nb * xstr + c] - ctr[p][c];
    }
    __syncthreads();
    int p = threadIdx.x / TPP;
    int og = (threadIdx.x % TPP) * 4;
    float gs[4], bt[4];
    #pragma unroll
    for (int j = 0; j < 4; ++j) {
        gs[j] = gamma[og + j] / sqrtf(1.f + 1e-5f);
        bt[j] = beta[og + j];
    }
    float base[4] = {0.f, 0.f, 0.f, 0.f};
    for (int c = 0; c < DIN; ++c) {
        float cv = ctr[p][c];
        #pragma unroll
        for (int j = 0; j < 4; ++j) base[j] += cv * w[(og + j) * C2 + DIN + c];
    }
    float acc[KNN][4];
    #pragma unroll
    for (int kk = 0; kk < KNN; ++kk)
        #pragma unroll
        for (int j = 0; j < 4; ++j) acc[kk][j] = base[j];
    for (int c = 0; c < DIN; ++c) {
        float w4[4];
        #pragma unroll
        for (int j = 0; j < 4; ++j) w4[j] = w[(og + j) * C2 + c];
        #pragma unroll
        for (int kk = 0; kk < KNN; ++kk) {
            float nv = nm[p][kk][c];
            #pragma unroll
            for (int j = 0; j < 4; ++j) acc[kk][j] += nv * w4[j];
        }
    }
    float best[4] = {-INFINITY, -INFINITY, -INFINITY, -INFINITY};
    #pragma unroll
    for (int kk = 0; kk < KNN; ++kk)
        #pragma unroll
        for (int j = 0; j < 4; ++j)
            best[j] = fmaxf(best[j], lrelu(acc[kk][j] * gs[j] + bt[j]));
    #pragma unroll
    for (int j = 0; j < 4; ++j)
        out[(long)(p0 + p) * 512 + outoff + og + j] = best[j];
}

// ---------------- uv GEMM: uv[r][j] = sum_k x[r][k] * Bcat[k][j] ----------
template <int DIN, int DOUT>
__global__ __launch_bounds__(256) void uvgemm_kernel(
    const float* __restrict__ x, int xoff, const float* __restrict__ w,
    float* __restrict__ uv) {
    constexpr int NC = 2 * DOUT;
    __shared__ float As[16][132];
    __shared__ float Bs[16][132];
    int r0 = blockIdx.y * 128;
    int c0 = blockIdx.x * 128;
    int tx = threadIdx.x & 15, ty = threadIdx.x >> 4;
    float acc[8][8] = {};
    #pragma unroll 1
    for (int kt = 0; kt < DIN / 16; ++kt) {
        int k0 = kt * 16;
        for (int e = threadIdx.x; e < 2048; e += 256) {
            int kk = e & 15, r = e >> 4;
            As[kk][r] = x[(long)(r0 + r) * 512 + xoff + k0 + kk];
            int jg = c0 + r;
            Bs[kk][r] = (jg < DOUT) ? w[(long)jg * (2 * DIN) + k0 + kk]
                                    : w[(long)(jg - DOUT) * (2 * DIN) + DIN + k0 + kk];
        }
        __syncthreads();
        #pragma unroll
        for (int kk = 0; kk < 16; ++kk) {
            float a[8], bb[8];
            *(float4*)&a[0] = *(float4*)&As[kk][ty * 8];
            *(float4*)&a[4] = *(float4*)&As[kk][ty * 8 + 4];
            *(float4*)&bb[0] = *(float4*)&Bs[kk][tx * 4];
            *(float4*)&bb[4] = *(float4*)&Bs[kk][64 + tx * 4];
            #pragma unroll
            for (int i = 0; i < 8; ++i)
                #pragma unroll
                for (int j = 0; j < 8; ++j) acc[i][j] += a[i] * bb[j];
        }
        __syncthreads();
    }
    int cb0 = c0 + tx * 4;
    int cb1 = c0 + 64 + tx * 4;
    #pragma unroll
    for (int i = 0; i < 8; ++i) {
        int r = r0 + ty * 8 + i;
        *(float4*)&uv[(long)r * NC + cb0] = *(float4*)&acc[i][0];
        *(float4*)&uv[(long)r * NC + cb1] = *(float4*)&acc[i][4];
    }
}

// ---------------- edge max epilogue: h = u[nb] - u[n] + v[n] --------------
template <int DOUT>
__global__ __launch_bounds__(256) void edgemax_kernel(
    const float* __restrict__ uv, const int* __restrict__ idx,
    const float* __restrict__ gamma, const float* __restrict__ beta,
    float* __restrict__ out, int outoff) {
    constexpr int NC = 2 * DOUT;
    constexpr int TPP = DOUT / 4;
    constexpr int TP = 256 / TPP;
    __shared__ int sidx[TP][KNN];
    int p0 = blockIdx.x * TP;
    for (int e = threadIdx.x; e < TP * KNN; e += 256)
        sidx[e / KNN][e % KNN] = idx[(long)(p0 + e / KNN) * KNN + (e % KNN)];
    __syncthreads();
    int p = threadIdx.x / TPP;
    int og = (threadIdx.x % TPP) * 4;
    int g = p0 + p;
    int base_pt = g & ~(N_PTS - 1);
    const float* rowg = uv + (long)g * NC;
    float4 u_n = *(const float4*)&rowg[og];
    float4 v_n = *(const float4*)&rowg[DOUT + og];
    float c0 = v_n.x - u_n.x, c1 = v_n.y - u_n.y;
    float c2 = v_n.z - u_n.z, c3 = v_n.w - u_n.w;
    const float rs = 1.f / sqrtf(1.f + 1e-5f);
    float gs0 = gamma[og + 0] * rs, gs1 = gamma[og + 1] * rs;
    float gs2 = gamma[og + 2] * rs, gs3 = gamma[og + 3] * rs;
    float bt0 = beta[og + 0], bt1 = beta[og + 1];
    float bt2 = beta[og + 2], bt3 = beta[og + 3];
    float b0 = -INFINITY, b1 = -INFINITY, b2 = -INFINITY, b3 = -INFINITY;
    #pragma unroll
    for (int kk = 0; kk < KNN; ++kk) {
        int nb = base_pt + sidx[p][kk];
        float4 ub = *(const float4*)&uv[(long)nb * NC + og];
        b0 = fmaxf(b0, lrelu((ub.x + c0) * gs0 + bt0));
        b1 = fmaxf(b1, lrelu((ub.y + c1) * gs1 + bt1));
        b2 = fmaxf(b2, lrelu((ub.z + c2) * gs2 + bt2));
        b3 = fmaxf(b3, lrelu((ub.w + c3) * gs3 + bt3));
    }
    float4 o4; o4.x = b0; o4.y = b1; o4.z = b2; o4.w = b3;
    *(float4*)&out[(long)g * 512 + outoff + og] = o4;
}

// ---------------- init h5 key buffer ----------------
__global__ void init_h5_kernel(unsigned* __restrict__ h5key) {
    int t = blockIdx.x * blockDim.x + threadIdx.x;
    if (t < BATCH * 1024) h5key[t] = 0u;
}

// ---------------- w5 GEMM + BN + lrelu + max over n, 128x128 tile ---------
__global__ __launch_bounds__(256) void w5max_kernel(
    const float* __restrict__ cat, const float* __restrict__ w5,
    const float* __restrict__ g5, const float* __restrict__ b5,
    unsigned* __restrict__ h5key) {
    __shared__ float As[16][132];
    __shared__ float Bs[16][132];
    int b = blockIdx.z;
    int n0 = blockIdx.y * 128, o0 = blockIdx.x * 128;
    int tx = threadIdx.x & 15, ty = threadIdx.x >> 4;
    const float* A = cat + (long)b * N_PTS * 512;
    float acc[8][8] = {};
    for (int kt = 0; kt < 32; ++kt) {
        int k0 = kt * 16;
        for (int e = threadIdx.x; e < 2048; e += 256) {
            int kk = e & 15, r = e >> 4;
            As[kk][r] = A[(long)(n0 + r) * 512 + k0 + kk];
            Bs[kk][r] = w5[(long)(o0 + r) * 512 + k0 + kk];
        }
        __syncthreads();
        #pragma unroll
        for (int kk = 0; kk < 16; ++kk) {
            float a[8], bb[8];
            *(float4*)&a[0] = *(float4*)&As[kk][ty * 8];
            *(float4*)&a[4] = *(float4*)&As[kk][ty * 8 + 4];
            *(float4*)&bb[0] = *(float4*)&Bs[kk][tx * 4];
            *(float4*)&bb[4] = *(float4*)&Bs[kk][64 + tx * 4];
            #pragma unroll
            for (int i = 0; i < 8; ++i)
                #pragma unroll
                for (int j = 0; j < 8; ++j) acc[i][j] += a[i] * bb[j];
        }
        __syncthreads();
    }
    float colmax[8];
    #pragma unroll
    for (int j = 0; j < 8; ++j) {
        int col_local = (j < 4) ? (tx * 4 + j) : (64 + tx * 4 + (j - 4));
        int o = o0 + col_local;
        float gsc = g5[o] / sqrtf(1.f + 1e-5f);
        float bto = b5[o];
        float m = -INFINITY;
        #pragma unroll
        for (int i = 0; i < 8; ++i)
            m = fmaxf(m, lrelu(acc[i][j] * gsc + bto));
        colmax[j] = m;
    }
    __syncthreads();
    float* red = &As[0][0];
    #pragma unroll
    for (int j = 0; j < 8; ++j) {
        int col_local = (j < 4) ? (tx * 4 + j) : (64 + tx * 4 + (j - 4));
        red[ty * 128 + col_local] = colmax[j];
    }
    __syncthreads();
    if (threadIdx.x < 128) {
        int col = threadIdx.x;
        float m = -INFINITY;
        #pragma unroll
        for (int t = 0; t < 16; ++t) m = fmaxf(m, red[t * 128 + col]);
        atomicMax(&h5key[b * 1024 + o0 + col], f2key(m));
    }
}

// ---------------- FC head ----------------
__global__ void fc1_kernel(const unsigned* __restrict__ h5key,
                           const float* __restrict__ fw1,
                           const float* __restrict__ fg1,
                           const float* __restrict__ fbt1,
                           float* __restrict__ f1) {
    int o = blockIdx.x * 256 + threadIdx.x;
    int b = blockIdx.y;
    if (o >= 512) return;
    float s = 0.f;
    for (int c = 0; c < 1024; ++c)
        s += key2f(h5key[b * 1024 + c]) * fw1[o * 1024 + c];
    float h = s * (fg1[o] / sqrtf(1.f + 1e-5f)) + fbt1[o];
    f1[b * 512 + o] = lrelu(h);
}

__global__ void fc2_kernel(const float* __restrict__ f1,
                           const float* __restrict__ fw2,
                           const float* __restrict__ fb2,
                           const float* __restrict__ fg2,
                           const float* __restrict__ fbt2,
                           float* __restrict__ f2) {
    int o = threadIdx.x;
    int b = blockIdx.x;
    float s = fb2[o];
    for (int c = 0; c < 512; ++c) s += f1[b * 512 + c] * fw2[o * 512 + c];
    float h = s * (fg2[o] / sqrtf(1.f + 1e-5f)) + fbt2[o];
    f2[b * 256 + o] = lrelu(h);
}

__global__ void fc3_kernel(const float* __restrict__ f2,
                           const float* __restrict__ fw3,
                           const float* __restrict__ fb3,
                           float* __restrict__ out) {
    int t = threadIdx.x;
    if (t >= BATCH * 3) return;
    int b = t / 3, o = t - b * 3;
    float s = fb3[o];
    for (int c = 0; c < 256; ++c) s += f2[b * 256 + c] * fw3[o * 256 + c];
    out[t] = s;
}

extern "C" void kernel_launch(void* const* d_in, const int* in_sizes, int n_in,
                              void* d_out, int out_size, void* d_ws, size_t ws_size,
                              hipStream_t stream) {
    const float* points = (const float*)d_in[0];
    const float* w1 = (const float*)d_in[2];
    const float* g1 = (const float*)d_in[3];
    const float* b1 = (const float*)d_in[4];
    const float* w2 = (const float*)d_in[5];
    const float* g2 = (const float*)d_in[6];
    const float* b2 = (const float*)d_in[7];
    const float* w3 = (const float*)d_in[8];
    const float* g3 = (const float*)d_in[9];
    const float* b3 = (const float*)d_in[10];
    const float* w4 = (const float*)d_in[11];
    const float* g4 = (const float*)d_in[12];
    const float* b4 = (const float*)d_in[13];
    const float* w5 = (const float*)d_in[14];
    const float* g5 = (const float*)d_in[15];
    const float* b5 = (const float*)d_in[16];
    const float* fw1 = (const float*)d_in[17];
    const float* fg1 = (const float*)d_in[18];
    const float* fbt1 = (const float*)d_in[19];
    const float* fw2 = (const float*)d_in[20];
    const float* fb2 = (const float*)d_in[21];
    const float* fg2 = (const float*)d_in[22];
    const float* fbt2 = (const float*)d_in[23];
    const float* fw3 = (const float*)d_in[24];
    const float* fb3 = (const float*)d_in[25];

    float* ws = (float*)d_ws;
    float* cat = ws;                                     // 4*4096*512
    float* sq = cat + (long)BATCH * N_PTS * 512;         // 16384
    unsigned* h5key = (unsigned*)(sq + BATCH * N_PTS);   // 4096
    float* f1 = (float*)(h5key + BATCH * 1024);          // 2048
    float* f2 = f1 + BATCH * 512;                        // 1024
    int* idxbuf = (int*)(f2 + BATCH * 256);              // 4*4096*10
    float* dist = (float*)(idxbuf + (long)BATCH * N_PTS * KNN); // 4*1024*4096
    float* uv = dist;   // alias: dist scratch is free once topk is done

    auto knn = [&](const float* xbase, int xstr, int D) {
        sq_kernel<<<64, 256, 0, stream>>>(xbase, xstr, D, sq);
        for (int r0 = 0; r0 < N_PTS; r0 += 1024) {
            dist_kernel<<<dim3(32, 8, BATCH), 256, 0, stream>>>(xbase, sq, dist, xstr, D, r0);
            topk_kernel<<<dim3(256, BATCH), 256, 0, stream>>>(dist, idxbuf, r0);
        }
    };

    // layer 1: points(3) -> o1 (64) at cat+0 (fused small kernel)
    knn(points, 3, 3);
    edgeconv_kernel<3, 64, 16, 16><<<N_PTS * BATCH / 16, 256, 0, stream>>>(
        points, 3, idxbuf, w1, g1, b1, cat, 0);

    // layer 2: o1(64) -> o2 (64) at cat+64
    knn(cat + 0, 512, 64);
    uvgemm_kernel<64, 64><<<dim3(1, 128), 256, 0, stream>>>(cat, 0, w2, uv);
    edgemax_kernel<64><<<1024, 256, 0, stream>>>(uv, idxbuf, g2, b2, cat, 64);

    // layer 3: o2(64) -> o3 (128) at cat+128
    knn(cat + 64, 512, 64);
    uvgemm_kernel<64, 128><<<dim3(2, 128), 256, 0, stream>>>(cat, 64, w3, uv);
    edgemax_kernel<128><<<2048, 256, 0, stream>>>(uv, idxbuf, g3, b3, cat, 128);

    // layer 4: o3(128) -> o4 (256) at cat+256
    knn(cat + 128, 512, 128);
    uvgemm_kernel<128, 256><<<dim3(4, 128), 256, 0, stream>>>(cat, 128, w4, uv);
    edgemax_kernel<256><<<4096, 256, 0, stream>>>(uv, idxbuf, g4, b4, cat, 256);

    // global feature
    init_h5_kernel<<<16, 256, 0, stream>>>(h5key);
    w5max_kernel<<<dim3(8, 32, BATCH), 256, 0, stream>>>(cat, w5, g5, b5, h5key);

    // FC head
    fc1_kernel<<<dim3(2, BATCH), 256, 0, stream>>>(h5key, fw1, fg1, fbt1, f1);
    fc2_kernel<<<BATCH, 256, 0, stream>>>(f1, fw2, fb2, fg2, fbt2, f2);
    fc3_kernel<<<1, 64, 0, stream>>>(f2, fw3, fb3, (float*)d_out);
}

// Round 5
// 3737.957 us; speedup vs baseline: 1.0261x; 1.0261x over previous
//
#include <hip/hip_runtime.h>
#include <math.h>

#define N_PTS 4096
#define BATCH 4
#define KNN 10

__device__ __forceinline__ bool better(float v1, int i1, float v2, int i2) {
    return (v1 > v2) || (v1 == v2 && i1 < i2);
}

__device__ __forceinline__ unsigned f2key(float x) {
    unsigned u = __float_as_uint(x);
    return (u & 0x80000000u) ? ~u : (u | 0x80000000u);
}
__device__ __forceinline__ float key2f(unsigned k) {
    unsigned u = (k & 0x80000000u) ? (k & 0x7FFFFFFFu) : ~k;
    return __uint_as_float(u);
}

__device__ __forceinline__ float lrelu(float h) { return (h > 0.f) ? h : 0.2f * h; }

// ---------------- squared norms ----------------
__global__ void sq_kernel(const float* __restrict__ x, int xstr, int D,
                          float* __restrict__ sq) {
    int g = blockIdx.x * blockDim.x + threadIdx.x;
    if (g >= BATCH * N_PTS) return;
    const float* row = x + (long)g * xstr;
    float s = 0.f;
    if ((D & 3) == 0) {
        for (int c = 0; c < D; c += 4) {
            float4 v = *(const float4*)&row[c];
            s += v.x * v.x + v.y * v.y + v.z * v.z + v.w * v.w;
        }
    } else {
        for (int c = 0; c < D; ++c) { float v = row[c]; s += v * v; }
    }
    sq[g] = s;
}

// ---------------- fused knn: dist tile + running top-(k+1), no dist buffer -
// Block: 32 rows x 1 batch. A rows resident in LDS; sweep 32 col-tiles of
// 128: GEMM tile (2x8/thread) -> dt in LDS -> 8 threads/row fold into
// private top-11. Final 8-lane pop-merge == jax.lax.top_k order; drop elem 0.
template <int D, int XSTR>
__global__ __launch_bounds__(256) void knn_kernel(
    const float* __restrict__ x, const float* __restrict__ sq,
    int* __restrict__ idxout) {
    constexpr int KTOT = (D + 15) & ~15;
    constexpr int ROWS = 32;
    __shared__ float As[KTOT][34];
    __shared__ float Bs[16][132];
    __shared__ float dt[ROWS][132];
    int b = blockIdx.y;
    const float* xb = x + (long)b * N_PTS * XSTR;
    const float* sqb = sq + b * N_PTS;
    int r0 = blockIdx.x * ROWS;
    int tid = threadIdx.x;
    int tx = tid & 15, ty = tid >> 4;
    for (int e = tid; e < ROWS * KTOT; e += 256) {
        int kk = e % KTOT, row = e / KTOT;
        As[kk][row] = (kk < D) ? xb[(long)(r0 + row) * XSTR + kk] : 0.f;
    }
    float sqr0 = sqb[r0 + ty * 2 + 0];
    float sqr1 = sqb[r0 + ty * 2 + 1];
    int srow = tid >> 3, s = tid & 7;
    float lv[11]; int li[11];
    #pragma unroll
    for (int j = 0; j < 11; ++j) { lv[j] = -INFINITY; li[j] = 0x7FFFFFFF; }
    __syncthreads();
    #pragma unroll 1
    for (int ct = 0; ct < N_PTS / 128; ++ct) {
        int c0 = ct * 128;
        float acc[2][8] = {};
        #pragma unroll 1
        for (int kt = 0; kt < KTOT / 16; ++kt) {
            int k0 = kt * 16;
            for (int e = tid; e < 2048; e += 256) {
                int kk = e & 15, col = e >> 4;
                int c = k0 + kk;
                Bs[kk][col] = (c < D) ? xb[(long)(c0 + col) * XSTR + c] : 0.f;
            }
            __syncthreads();
            #pragma unroll
            for (int kk = 0; kk < 16; ++kk) {
                float a0 = As[k0 + kk][ty * 2 + 0];
                float a1 = As[k0 + kk][ty * 2 + 1];
                float bb[8];
                *(float4*)&bb[0] = *(float4*)&Bs[kk][tx * 4];
                *(float4*)&bb[4] = *(float4*)&Bs[kk][64 + tx * 4];
                #pragma unroll
                for (int j = 0; j < 8; ++j) {
                    acc[0][j] += a0 * bb[j];
                    acc[1][j] += a1 * bb[j];
                }
            }
            __syncthreads();
        }
        float sqc[8];
        #pragma unroll
        for (int j = 0; j < 4; ++j) {
            sqc[j] = sqb[c0 + tx * 4 + j];
            sqc[4 + j] = sqb[c0 + 64 + tx * 4 + j];
        }
        #pragma unroll
        for (int r = 0; r < 2; ++r) {
            float sr = r ? sqr1 : sqr0;
            float4 v0, v1;
            v0.x = 2.f * acc[r][0] - sr - sqc[0];
            v0.y = 2.f * acc[r][1] - sr - sqc[1];
            v0.z = 2.f * acc[r][2] - sr - sqc[2];
            v0.w = 2.f * acc[r][3] - sr - sqc[3];
            v1.x = 2.f * acc[r][4] - sr - sqc[4];
            v1.y = 2.f * acc[r][5] - sr - sqc[5];
            v1.z = 2.f * acc[r][6] - sr - sqc[6];
            v1.w = 2.f * acc[r][7] - sr - sqc[7];
            *(float4*)&dt[ty * 2 + r][tx * 4] = v0;
            *(float4*)&dt[ty * 2 + r][64 + tx * 4] = v1;
        }
        __syncthreads();
        #pragma unroll
        for (int i = 0; i < 16; ++i) {
            float v = dt[srow][s + 8 * i];
            int c = c0 + s + 8 * i;
            if (better(v, c, lv[10], li[10])) {
                lv[10] = v; li[10] = c;
                #pragma unroll
                for (int j = 10; j > 0; --j) {
                    if (better(lv[j], li[j], lv[j - 1], li[j - 1])) {
                        float tv = lv[j]; lv[j] = lv[j - 1]; lv[j - 1] = tv;
                        int ti = li[j]; li[j] = li[j - 1]; li[j - 1] = ti;
                    }
                }
            }
        }
        __syncthreads();
    }
    // 8-lane pop-merge: round 0 discards the self/top element, rounds 1..10
    // emit neighbor positions 0..9 (q&7 -> lane, q>>3 -> slot).
    int keep0 = 0, keep1 = 0;
    #pragma unroll
    for (int r = 0; r < 11; ++r) {
        float bv = lv[0]; int bi = li[0];
        #pragma unroll
        for (int off = 4; off > 0; off >>= 1) {
            float ov = __shfl_xor(bv, off);
            int oi = __shfl_xor(bi, off);
            if (better(ov, oi, bv, bi)) { bv = ov; bi = oi; }
        }
        if (li[0] == bi) {
            #pragma unroll
            for (int j = 0; j < 10; ++j) { lv[j] = lv[j + 1]; li[j] = li[j + 1]; }
            lv[10] = -INFINITY; li[10] = 0x7FFFFFFF;
        }
        if (r > 0) {
            int q = r - 1;
            if ((q & 7) == s) { if (q < 8) keep0 = bi; else keep1 = bi; }
        }
    }
    long gr = (long)b * N_PTS + r0 + srow;
    idxout[gr * KNN + s] = keep0;
    if (s < 2) idxout[gr * KNN + 8 + s] = keep1;
}

// ---------------- edge conv L1 (DIN=3, fused path) ----------------
template <int DIN, int DOUT, int PTS, int TPP>
__global__ __launch_bounds__(256) void edgeconv_kernel(
    const float* __restrict__ x, int xstr, const int* __restrict__ idx,
    const float* __restrict__ w, const float* __restrict__ gamma,
    const float* __restrict__ beta, float* __restrict__ out, int outoff) {
    constexpr int DP = DIN + 1;
    constexpr int C2 = 2 * DIN;
    __shared__ float ctr[PTS][DP];
    __shared__ float nm[PTS][KNN][DP];
    int p0 = blockIdx.x * PTS;
    for (int e = threadIdx.x; e < PTS * DIN; e += 256) {
        int p = e / DIN, c = e - p * DIN;
        ctr[p][c] = x[(long)(p0 + p) * xstr + c];
    }
    __syncthreads();
    for (int e = threadIdx.x; e < PTS * KNN * DIN; e += 256) {
        int p = e / (KNN * DIN);
        int rem = e - p * (KNN * DIN);
        int kk = rem / DIN, c = rem - kk * DIN;
        int g = p0 + p;
        int nb = (g & ~(N_PTS - 1)) + idx[(long)g * KNN + kk];
        nm[p][kk][c] = x[(long)nb * xstr + c] - ctr[p][c];
    }
    __syncthreads();
    int p = threadIdx.x / TPP;
    int og = (threadIdx.x % TPP) * 4;
    float gs[4], bt[4];
    #pragma unroll
    for (int j = 0; j < 4; ++j) {
        gs[j] = gamma[og + j] / sqrtf(1.f + 1e-5f);
        bt[j] = beta[og + j];
    }
    float base[4] = {0.f, 0.f, 0.f, 0.f};
    for (int c = 0; c < DIN; ++c) {
        float cv = ctr[p][c];
        #pragma unroll
        for (int j = 0; j < 4; ++j) base[j] += cv * w[(og + j) * C2 + DIN + c];
    }
    float acc[KNN][4];
    #pragma unroll
    for (int kk = 0; kk < KNN; ++kk)
        #pragma unroll
        for (int j = 0; j < 4; ++j) acc[kk][j] = base[j];
    for (int c = 0; c < DIN; ++c) {
        float w4[4];
        #pragma unroll
        for (int j = 0; j < 4; ++j) w4[j] = w[(og + j) * C2 + c];
        #pragma unroll
        for (int kk = 0; kk < KNN; ++kk) {
            float nv = nm[p][kk][c];
            #pragma unroll
            for (int j = 0; j < 4; ++j) acc[kk][j] += nv * w4[j];
        }
    }
    float best[4] = {-INFINITY, -INFINITY, -INFINITY, -INFINITY};
    #pragma unroll
    for (int kk = 0; kk < KNN; ++kk)
        #pragma unroll
        for (int j = 0; j < 4; ++j)
            best[j] = fmaxf(best[j], lrelu(acc[kk][j] * gs[j] + bt[j]));
    #pragma unroll
    for (int j = 0; j < 4; ++j)
        out[(long)(p0 + p) * 512 + outoff + og + j] = best[j];
}

// ---------------- uv GEMM: uv[r][j] = sum_k x[r][k] * Bcat[k][j] ----------
template <int DIN, int DOUT>
__global__ __launch_bounds__(256) void uvgemm_kernel(
    const float* __restrict__ x, int xoff, const float* __restrict__ w,
    float* __restrict__ uv) {
    constexpr int NC = 2 * DOUT;
    __shared__ float As[16][132];
    __shared__ float Bs[16][132];
    int r0 = blockIdx.y * 128;
    int c0 = blockIdx.x * 128;
    int tx = threadIdx.x & 15, ty = threadIdx.x >> 4;
    float acc[8][8] = {};
    #pragma unroll 1
    for (int kt = 0; kt < DIN / 16; ++kt) {
        int k0 = kt * 16;
        for (int e = threadIdx.x; e < 2048; e += 256) {
            int kk = e & 15, r = e >> 4;
            As[kk][r] = x[(long)(r0 + r) * 512 + xoff + k0 + kk];
            int jg = c0 + r;
            Bs[kk][r] = (jg < DOUT) ? w[(long)jg * (2 * DIN) + k0 + kk]
                                    : w[(long)(jg - DOUT) * (2 * DIN) + DIN + k0 + kk];
        }
        __syncthreads();
        #pragma unroll
        for (int kk = 0; kk < 16; ++kk) {
            float a[8], bb[8];
            *(float4*)&a[0] = *(float4*)&As[kk][ty * 8];
            *(float4*)&a[4] = *(float4*)&As[kk][ty * 8 + 4];
            *(float4*)&bb[0] = *(float4*)&Bs[kk][tx * 4];
            *(float4*)&bb[4] = *(float4*)&Bs[kk][64 + tx * 4];
            #pragma unroll
            for (int i = 0; i < 8; ++i)
                #pragma unroll
                for (int j = 0; j < 8; ++j) acc[i][j] += a[i] * bb[j];
        }
        __syncthreads();
    }
    int cb0 = c0 + tx * 4;
    int cb1 = c0 + 64 + tx * 4;
    #pragma unroll
    for (int i = 0; i < 8; ++i) {
        int r = r0 + ty * 8 + i;
        *(float4*)&uv[(long)r * NC + cb0] = *(float4*)&acc[i][0];
        *(float4*)&uv[(long)r * NC + cb1] = *(float4*)&acc[i][4];
    }
}

// ---------------- edge max epilogue: h = u[nb] - u[n] + v[n] --------------
template <int DOUT>
__global__ __launch_bounds__(256) void edgemax_kernel(
    const float* __restrict__ uv, const int* __restrict__ idx,
    const float* __restrict__ gamma, const float* __restrict__ beta,
    float* __restrict__ out, int outoff) {
    constexpr int NC = 2 * DOUT;
    constexpr int TPP = DOUT / 4;
    constexpr int TP = 256 / TPP;
    __shared__ int sidx[TP][KNN];
    int p0 = blockIdx.x * TP;
    for (int e = threadIdx.x; e < TP * KNN; e += 256)
        sidx[e / KNN][e % KNN] = idx[(long)(p0 + e / KNN) * KNN + (e % KNN)];
    __syncthreads();
    int p = threadIdx.x / TPP;
    int og = (threadIdx.x % TPP) * 4;
    int g = p0 + p;
    int base_pt = g & ~(N_PTS - 1);
    const float* rowg = uv + (long)g * NC;
    float4 u_n = *(const float4*)&rowg[og];
    float4 v_n = *(const float4*)&rowg[DOUT + og];
    float c0 = v_n.x - u_n.x, c1 = v_n.y - u_n.y;
    float c2 = v_n.z - u_n.z, c3 = v_n.w - u_n.w;
    const float rs = 1.f / sqrtf(1.f + 1e-5f);
    float gs0 = gamma[og + 0] * rs, gs1 = gamma[og + 1] * rs;
    float gs2 = gamma[og + 2] * rs, gs3 = gamma[og + 3] * rs;
    float bt0 = beta[og + 0], bt1 = beta[og + 1];
    float bt2 = beta[og + 2], bt3 = beta[og + 3];
    float b0 = -INFINITY, b1 = -INFINITY, b2 = -INFINITY, b3 = -INFINITY;
    #pragma unroll
    for (int kk = 0; kk < KNN; ++kk) {
        int nb = base_pt + sidx[p][kk];
        float4 ub = *(const float4*)&uv[(long)nb * NC + og];
        b0 = fmaxf(b0, lrelu((ub.x + c0) * gs0 + bt0));
        b1 = fmaxf(b1, lrelu((ub.y + c1) * gs1 + bt1));
        b2 = fmaxf(b2, lrelu((ub.z + c2) * gs2 + bt2));
        b3 = fmaxf(b3, lrelu((ub.w + c3) * gs3 + bt3));
    }
    float4 o4; o4.x = b0; o4.y = b1; o4.z = b2; o4.w = b3;
    *(float4*)&out[(long)g * 512 + outoff + og] = o4;
}

// ---------------- init h5 key buffer ----------------
__global__ void init_h5_kernel(unsigned* __restrict__ h5key) {
    int t = blockIdx.x * blockDim.x + threadIdx.x;
    if (t < BATCH * 1024) h5key[t] = 0u;
}

// ---------------- w5 GEMM + BN + lrelu + max over n, 128x128 tile ---------
__global__ __launch_bounds__(256) void w5max_kernel(
    const float* __restrict__ cat, const float* __restrict__ w5,
    const float* __restrict__ g5, const float* __restrict__ b5,
    unsigned* __restrict__ h5key) {
    __shared__ float As[16][132];
    __shared__ float Bs[16][132];
    int b = blockIdx.z;
    int n0 = blockIdx.y * 128, o0 = blockIdx.x * 128;
    int tx = threadIdx.x & 15, ty = threadIdx.x >> 4;
    const float* A = cat + (long)b * N_PTS * 512;
    float acc[8][8] = {};
    for (int kt = 0; kt < 32; ++kt) {
        int k0 = kt * 16;
        for (int e = threadIdx.x; e < 2048; e += 256) {
            int kk = e & 15, r = e >> 4;
            As[kk][r] = A[(long)(n0 + r) * 512 + k0 + kk];
            Bs[kk][r] = w5[(long)(o0 + r) * 512 + k0 + kk];
        }
        __syncthreads();
        #pragma unroll
        for (int kk = 0; kk < 16; ++kk) {
            float a[8], bb[8];
            *(float4*)&a[0] = *(float4*)&As[kk][ty * 8];
            *(float4*)&a[4] = *(float4*)&As[kk][ty * 8 + 4];
            *(float4*)&bb[0] = *(float4*)&Bs[kk][tx * 4];
            *(float4*)&bb[4] = *(float4*)&Bs[kk][64 + tx * 4];
            #pragma unroll
            for (int i = 0; i < 8; ++i)
                #pragma unroll
                for (int j = 0; j < 8; ++j) acc[i][j] += a[i] * bb[j];
        }
        __syncthreads();
    }
    float colmax[8];
    #pragma unroll
    for (int j = 0; j < 8; ++j) {
        int col_local = (j < 4) ? (tx * 4 + j) : (64 + tx * 4 + (j - 4));
        int o = o0 + col_local;
        float gsc = g5[o] / sqrtf(1.f + 1e-5f);
        float bto = b5[o];
        float m = -INFINITY;
        #pragma unroll
        for (int i = 0; i < 8; ++i)
            m = fmaxf(m, lrelu(acc[i][j] * gsc + bto));
        colmax[j] = m;
    }
    __syncthreads();
    float* red = &As[0][0];
    #pragma unroll
    for (int j = 0; j < 8; ++j) {
        int col_local = (j < 4) ? (tx * 4 + j) : (64 + tx * 4 + (j - 4));
        red[ty * 128 + col_local] = colmax[j];
    }
    __syncthreads();
    if (threadIdx.x < 128) {
        int col = threadIdx.x;
        float m = -INFINITY;
        #pragma unroll
        for (int t = 0; t < 16; ++t) m = fmaxf(m, red[t * 128 + col]);
        atomicMax(&h5key[b * 1024 + o0 + col], f2key(m));
    }
}

// ---------------- FC head ----------------
__global__ void fc1_kernel(const unsigned* __restrict__ h5key,
                           const float* __restrict__ fw1,
                           const float* __restrict__ fg1,
                           const float* __restrict__ fbt1,
                           float* __restrict__ f1) {
    int o = blockIdx.x * 256 + threadIdx.x;
    int b = blockIdx.y;
    if (o >= 512) return;
    float s = 0.f;
    for (int c = 0; c < 1024; ++c)
        s += key2f(h5key[b * 1024 + c]) * fw1[o * 1024 + c];
    float h = s * (fg1[o] / sqrtf(1.f + 1e-5f)) + fbt1[o];
    f1[b * 512 + o] = lrelu(h);
}

__global__ void fc2_kernel(const float* __restrict__ f1,
                           const float* __restrict__ fw2,
                           const float* __restrict__ fb2,
                           const float* __restrict__ fg2,
                           const float* __restrict__ fbt2,
                           float* __restrict__ f2) {
    int o = threadIdx.x;
    int b = blockIdx.x;
    float s = fb2[o];
    for (int c = 0; c < 512; ++c) s += f1[b * 512 + c] * fw2[o * 512 + c];
    float h = s * (fg2[o] / sqrtf(1.f + 1e-5f)) + fbt2[o];
    f2[b * 256 + o] = lrelu(h);
}

__global__ void fc3_kernel(const float* __restrict__ f2,
                           const float* __restrict__ fw3,
                           const float* __restrict__ fb3,
                           float* __restrict__ out) {
    int t = threadIdx.x;
    if (t >= BATCH * 3) return;
    int b = t / 3, o = t - b * 3;
    float s = fb3[o];
    for (int c = 0; c < 256; ++c) s += f2[b * 256 + c] * fw3[o * 256 + c];
    out[t] = s;
}

extern "C" void kernel_launch(void* const* d_in, const int* in_sizes, int n_in,
                              void* d_out, int out_size, void* d_ws, size_t ws_size,
                              hipStream_t stream) {
    const float* points = (const float*)d_in[0];
    const float* w1 = (const float*)d_in[2];
    const float* g1 = (const float*)d_in[3];
    const float* b1 = (const float*)d_in[4];
    const float* w2 = (const float*)d_in[5];
    const float* g2 = (const float*)d_in[6];
    const float* b2 = (const float*)d_in[7];
    const float* w3 = (const float*)d_in[8];
    const float* g3 = (const float*)d_in[9];
    const float* b3 = (const float*)d_in[10];
    const float* w4 = (const float*)d_in[11];
    const float* g4 = (const float*)d_in[12];
    const float* b4 = (const float*)d_in[13];
    const float* w5 = (const float*)d_in[14];
    const float* g5 = (const float*)d_in[15];
    const float* b5 = (const float*)d_in[16];
    const float* fw1 = (const float*)d_in[17];
    const float* fg1 = (const float*)d_in[18];
    const float* fbt1 = (const float*)d_in[19];
    const float* fw2 = (const float*)d_in[20];
    const float* fb2 = (const float*)d_in[21];
    const float* fg2 = (const float*)d_in[22];
    const float* fbt2 = (const float*)d_in[23];
    const float* fw3 = (const float*)d_in[24];
    const float* fb3 = (const float*)d_in[25];

    float* ws = (float*)d_ws;
    float* cat = ws;                                     // 4*4096*512
    float* sq = cat + (long)BATCH * N_PTS * 512;         // 16384
    unsigned* h5key = (unsigned*)(sq + BATCH * N_PTS);   // 4096
    float* f1 = (float*)(h5key + BATCH * 1024);          // 2048
    float* f2 = f1 + BATCH * 512;                        // 1024
    int* idxbuf = (int*)(f2 + BATCH * 256);              // 4*4096*10
    float* uv = (float*)(idxbuf + (long)BATCH * N_PTS * KNN); // <= 4*4096*512

    // layer 1: points(3) -> o1 (64) at cat+0
    sq_kernel<<<64, 256, 0, stream>>>(points, 3, 3, sq);
    knn_kernel<3, 3><<<dim3(128, BATCH), 256, 0, stream>>>(points, sq, idxbuf);
    edgeconv_kernel<3, 64, 16, 16><<<N_PTS * BATCH / 16, 256, 0, stream>>>(
        points, 3, idxbuf, w1, g1, b1, cat, 0);

    // layer 2: o1(64) -> o2 (64) at cat+64
    sq_kernel<<<64, 256, 0, stream>>>(cat + 0, 512, 64, sq);
    knn_kernel<64, 512><<<dim3(128, BATCH), 256, 0, stream>>>(cat + 0, sq, idxbuf);
    uvgemm_kernel<64, 64><<<dim3(1, 128), 256, 0, stream>>>(cat, 0, w2, uv);
    edgemax_kernel<64><<<1024, 256, 0, stream>>>(uv, idxbuf, g2, b2, cat, 64);

    // layer 3: o2(64) -> o3 (128) at cat+128
    sq_kernel<<<64, 256, 0, stream>>>(cat + 64, 512, 64, sq);
    knn_kernel<64, 512><<<dim3(128, BATCH), 256, 0, stream>>>(cat + 64, sq, idxbuf);
    uvgemm_kernel<64, 128><<<dim3(2, 128), 256, 0, stream>>>(cat, 64, w3, uv);
    edgemax_kernel<128><<<2048, 256, 0, stream>>>(uv, idxbuf, g3, b3, cat, 128);

    // layer 4: o3(128) -> o4 (256) at cat+256
    sq_kernel<<<64, 256, 0, stream>>>(cat + 128, 512, 128, sq);
    knn_kernel<128, 512><<<dim3(128, BATCH), 256, 0, stream>>>(cat + 128, sq, idxbuf);
    uvgemm_kernel<128, 256><<<dim3(4, 128), 256, 0, stream>>>(cat, 128, w4, uv);
    edgemax_kernel<256><<<4096, 256, 0, stream>>>(uv, idxbuf, g4, b4, cat, 256);

    // global feature
    init_h5_kernel<<<16, 256, 0, stream>>>(h5key);
    w5max_kernel<<<dim3(8, 32, BATCH), 256, 0, stream>>>(cat, w5, g5, b5, h5key);

    // FC head
    fc1_kernel<<<dim3(2, BATCH), 256, 0, stream>>>(h5key, fw1, fg1, fbt1, f1);
    fc2_kernel<<<BATCH, 256, 0, stream>>>(f1, fw2, fb2, fg2, fbt2, f2);
    fc3_kernel<<<1, 64, 0, stream>>>(f2, fw3, fb3, (float*)d_out);
}